// Round 2
// baseline (143.219 us; speedup 1.0000x reference)
//
#include <hip/hip_runtime.h>
#include <hip/hip_fp16.h>

typedef _Float16 half8v __attribute__((ext_vector_type(8)));
typedef _Float16 half2v __attribute__((ext_vector_type(2)));
typedef float f32x4 __attribute__((ext_vector_type(4)));

// one DPP butterfly-add stage (lane ^= 1) within 16-lane rows — pure VALU
#define DPP_XADD(x, ctrl)                                                          \
  x += __builtin_bit_cast(float, __builtin_amdgcn_mov_dpp(                         \
           __builtin_bit_cast(int, x), ctrl, 0xf, 0xf, true))

#define ISSUE_READS(slot, offw)                                                    \
  do {                                                                             \
    const _Float16* xi_ = &xh[((offw) >> 16) + eoff];                              \
    const _Float16* xj_ = &xh[((offw) & 0xffffu) + eoff];                          \
    xia[slot][0] = *(const half8v*)xi_;                                            \
    xia[slot][1] = *(const half8v*)(xi_ + 32);                                     \
    xja[slot][0] = *(const half8v*)xj_;                                            \
    xja[slot][1] = *(const half8v*)(xj_ + 32);                                     \
  } while (0)

__global__ __launch_bounds__(256) void afm_fused(
    const float* __restrict__ x, const float* __restrict__ W,
    const float* __restrict__ bvec, const float* __restrict__ hvec,
    const float* __restrict__ pvec, float* __restrict__ out) {
  // LDS: 5760 + 3136 + 3136 + 48 + 25088 = 37168 B -> 4 blocks/CU
  __shared__ __align__(16) _Float16 xh[40 * 72];    // row stride 144 B (16B-aligned)
  __shared__ __align__(16) unsigned int tblu[784];  // packed half-offsets (ri*72)<<16|(ci*72)
  __shared__ __align__(16) float s2s[784];
  __shared__ float red[12];
  __shared__ __align__(16) union WP {
    float w[64 * 65];     // W f32 staging (16.6 KB), dead after frag build
    float part[784 * 8];  // per-pair partial scores (25 KB), phase A -> B
  } u;

  const int tid = threadIdx.x;
  const int b = blockIdx.x;
  const int lane = tid & 63;
  const int wid = tid >> 6;
  const int m = lane & 15, kg = lane >> 4;

  // ---- stage x[b] (40x64 f32) -> LDS fp16, row stride 72 halves ----
  const float4* xg = (const float4*)(x + b * 2560);
#pragma unroll
  for (int it = 0; it < 3; ++it) {
    int g = tid + it * 256;
    if (g < 640) {
      float4 v = xg[g];
      int f = g >> 4, e4 = g & 15;
      half2v* dst = (half2v*)&xh[f * 72 + e4 * 4];
      dst[0] = __builtin_bit_cast(half2v, __builtin_amdgcn_cvt_pkrtz(v.x, v.y));
      dst[1] = __builtin_bit_cast(half2v, __builtin_amdgcn_cvt_pkrtz(v.z, v.w));
    }
  }
  // ---- stage W (64x64 f32) coalesced -> LDS [64][65] (conflict-free column reads) ----
#pragma unroll
  for (int it = 0; it < 4; ++it) {
    int g = tid + it * 256;
    float4 v = ((const float4*)W)[g];
    int e = g >> 4, u4 = (g & 15) * 4;
    float* dst = &u.w[e * 65 + u4];
    dst[0] = v.x; dst[1] = v.y; dst[2] = v.z; dst[3] = v.w;
  }
  // ---- pair table: analytic triu index -> packed half-offsets ----
  for (int p = tid; p < 784; p += 256) {
    int pc = p > 779 ? 779 : p;
    int i = (int)((79.0f - sqrtf(6241.0f - 8.0f * (float)pc)) * 0.5f);
    i = i < 0 ? 0 : (i > 38 ? 38 : i);
    while (i > 0 && (39 * i - (i * (i - 1)) / 2) > pc) --i;
    while ((39 * (i + 1) - ((i + 1) * i) / 2) <= pc) ++i;
    int base = 39 * i - (i * (i - 1)) / 2;
    int j = i + 1 + (pc - base);
    tblu[p] = ((unsigned)(i * 72) << 16) | (unsigned)(j * 72);
  }
  __syncthreads();

  // ---- build W/pvec MFMA B-fragments from LDS (fp16), bias/h to regs ----
  half8v wf[2][4];
#pragma unroll
  for (int ks = 0; ks < 2; ++ks)
#pragma unroll
    for (int nt = 0; nt < 4; ++nt) {
      const float* src = &u.w[(ks * 32 + kg * 8) * 65 + nt * 16 + m];
      half2v* hp = (half2v*)&wf[ks][nt];
      hp[0] = __builtin_bit_cast(half2v, __builtin_amdgcn_cvt_pkrtz(src[0], src[65]));
      hp[1] = __builtin_bit_cast(half2v, __builtin_amdgcn_cvt_pkrtz(src[130], src[195]));
      hp[2] = __builtin_bit_cast(half2v, __builtin_amdgcn_cvt_pkrtz(src[260], src[325]));
      hp[3] = __builtin_bit_cast(half2v, __builtin_amdgcn_cvt_pkrtz(src[390], src[455]));
    }
  half8v pf[2];
#pragma unroll
  for (int ks = 0; ks < 2; ++ks) {
    half2v* hp = (half2v*)&pf[ks];
#pragma unroll
    for (int jj = 0; jj < 4; ++jj) {
      int k = ks * 32 + kg * 8 + jj * 2;
      float a = (m == 0) ? pvec[k] : 0.f;
      float c = (m == 0) ? pvec[k + 1] : 0.f;
      hp[jj] = __builtin_bit_cast(half2v, __builtin_amdgcn_cvt_pkrtz(a, c));
    }
  }
  float bu[4], hu[4];
#pragma unroll
  for (int nt = 0; nt < 4; ++nt) {
    int uu = nt * 16 + m;
    bu[nt] = bvec[uu];
    hu[nt] = hvec[uu];
  }

  // ---- pipeline prologue (xh/tblu valid since barrier above) ----
  const int eoff = kg * 8;
  unsigned int off[2];
  half8v xia[2][2], xja[2][2];
  {
    int p0 = 16 * wid + m;                       // tile 0 of this wave (<784)
    off[0] = tblu[p0];
    ISSUE_READS(0, off[0]);
    int p1 = 16 * (wid + 4) + m;
    p1 = p1 > 783 ? 783 : p1;
    off[1] = tblu[p1];
  }
  __syncthreads();  // all waves done reading u.w -> safe to write u.part

  float* part = u.part;
  // ---- phase A: 13 tiles/wave, 2-deep software pipeline ----
#pragma unroll
  for (int i = 0; i < 13; ++i) {
    const int cur = i & 1, nxt = cur ^ 1;
    if (i < 12) ISSUE_READS(nxt, off[nxt]);
    if (i < 11) {
      int pn = 16 * (wid + 4 * (i + 2)) + m;
      pn = pn > 783 ? 783 : pn;
      off[cur] = tblu[pn];
    }
    half8v a0 = xia[cur][0] * xja[cur][0];   // ip, e = kg*8+j
    half8v a1 = xia[cur][1] * xja[cur][1];   // ip, e = 32+kg*8+j
    f32x4 acc[4];
#pragma unroll
    for (int nt = 0; nt < 4; ++nt) {
      acc[nt] = (f32x4){bu[nt], bu[nt], bu[nt], bu[nt]};
      acc[nt] = __builtin_amdgcn_mfma_f32_16x16x32_f16(a0, wf[0][nt], acc[nt], 0, 0, 0);
      acc[nt] = __builtin_amdgcn_mfma_f32_16x16x32_f16(a1, wf[1][nt], acc[nt], 0, 0, 0);
    }
    f32x4 accp = (f32x4){0.f, 0.f, 0.f, 0.f};
    accp = __builtin_amdgcn_mfma_f32_16x16x32_f16(a0, pf[0], accp, 0, 0, 0);
    accp = __builtin_amdgcn_mfma_f32_16x16x32_f16(a1, pf[1], accp, 0, 0, 0);

    const int t16 = 16 * (wid + 4 * i);
#pragma unroll
    for (int r = 0; r < 4; ++r) {
      float s = fmaxf(acc[0][r], 0.f) * hu[0] + fmaxf(acc[1][r], 0.f) * hu[1] +
                fmaxf(acc[2][r], 0.f) * hu[2] + fmaxf(acc[3][r], 0.f) * hu[3];
      DPP_XADD(s, 0xB1);  // lane ^= 1: pairwise u-sum -> 8 partials per pair
      int pr = t16 + kg * 4 + r;
      if (pr < 780) {
        if ((m & 1) == 0) part[pr * 8 + (m >> 1)] = s;
        if (m == 0) s2s[pr] = accp[r];  // col 0 of pvec-MFMA = ip . pvec
      }
    }
  }
  __syncthreads();

  // ---- phase B: finish score sums (regs), softmax over 780, weighted s2 ----
  float sv[4];
  float mx = -1e30f;
#pragma unroll
  for (int k2 = 0; k2 < 4; ++k2) {
    int p = tid + k2 * 256;
    if (p < 780) {
      const f32x4* pp = (const f32x4*)&part[p * 8];
      f32x4 lo = pp[0], hi = pp[1];
      float s = ((lo[0] + lo[1]) + (lo[2] + lo[3])) + ((hi[0] + hi[1]) + (hi[2] + hi[3]));
      sv[k2] = s;
      mx = fmaxf(mx, s);
    } else {
      sv[k2] = -1e30f;
    }
  }
#pragma unroll
  for (int o = 32; o; o >>= 1) mx = fmaxf(mx, __shfl_xor(mx, o));
  if (lane == 0) red[wid] = mx;
  __syncthreads();
  mx = fmaxf(fmaxf(red[0], red[1]), fmaxf(red[2], red[3]));
  float num = 0.f, den = 0.f;
#pragma unroll
  for (int k2 = 0; k2 < 4; ++k2) {
    int p = tid + k2 * 256;
    if (p < 780) {
      float e = __expf(sv[k2] - mx);
      num += e * s2s[p];
      den += e;
    }
  }
#pragma unroll
  for (int o = 32; o; o >>= 1) {
    num += __shfl_xor(num, o);
    den += __shfl_xor(den, o);
  }
  if (lane == 0) { red[4 + wid] = num; red[8 + wid] = den; }
  __syncthreads();
  if (tid == 0)
    out[b] = (red[4] + red[5] + red[6] + red[7]) /
             (red[8] + red[9] + red[10] + red[11]);
}

extern "C" void kernel_launch(void* const* d_in, const int* in_sizes, int n_in,
                              void* d_out, int out_size, void* d_ws, size_t ws_size,
                              hipStream_t stream) {
  const float* x    = (const float*)d_in[0];  // [4096,40,64]
  const float* W    = (const float*)d_in[1];  // [64,64]
  const float* bvec = (const float*)d_in[2];  // [64]
  const float* hvec = (const float*)d_in[3];  // [64,1]
  const float* pvec = (const float*)d_in[4];  // [64,1]
  float* out = (float*)d_out;                 // [4096,1]

  hipLaunchKernelGGL(afm_fused, dim3(4096), dim3(256), 0, stream,
                     x, W, bvec, hvec, pvec, out);
}